// Round 1
// 112.771 us; speedup vs baseline: 1.0627x; 1.0627x over previous
//
#include <hip/hip_runtime.h>
#include <cstdint>

#define DD 24
#define AA 13824          // 24*24*24
#define NF4 3456          // AA/4
#define BLOCK 1024
#define TOPK 60           // output rows per batch (unchanged)
#define NSEL 20           // only the first NMS_TOPK=20 valid candidates can ever be kept:
                          // valid scores (>THRESH) are strictly greater than invalid ones,
                          // so top-20-by-value contains the whole cand set of the reference.
#define THRESH 0.15f
#define NMS_THR 0.05f
#define NBINS 4096
#define BUFCAP 2048

__device__ __forceinline__ unsigned skey(float f) {
    unsigned u = __float_as_uint(f);
    return (u & 0x80000000u) ? ~u : (u | 0x80000000u);
}

__global__ __launch_bounds__(BLOCK, 4) void detpost(
    const float* __restrict__ cls,
    const float* __restrict__ shp,
    const float* __restrict__ off,
    float* __restrict__ out)
{
    __shared__ int      s_hist[NBINS];
    __shared__ int      s_S[257];
    __shared__ int      s_wsum[4];
    __shared__ int      s_seg;
    __shared__ int      s_bt;
    __shared__ int      s_cnt;
    __shared__ float    s_bufv[BUFCAP];
    __shared__ int      s_bufi[BUFCAP];
    __shared__ float    s_topv[NSEL];
    __shared__ int      s_topi[NSEL];
    __shared__ float    s_lo[3][NSEL], s_hi[3][NSEL], s_vol[NSEL];
    __shared__ float    s_det[NSEL][8];      // 1, score, cz, cy, cx, ez, ey, ex
    __shared__ unsigned s_m[NSEL];           // 20-bit suppression masks
    __shared__ unsigned s_candmask, s_keptmask;

    const int b   = blockIdx.x;
    const int tid = threadIdx.x;

    for (int i = tid; i < NBINS; i += BLOCK) s_hist[i] = 0;
    if (tid == 0) { s_cnt = 0; s_seg = 0; s_S[256] = 0; }
    __syncthreads();

    // ---- Pass 1: load cls into registers + histogram of top-12-bit sortable keys
    const float4* cls4 = (const float4*)(cls + (size_t)b * AA);
    const bool has3 = (tid + 3072) < NF4;    // NF4 = 3456: threads 0..383
    float4 r0 = cls4[tid];
    float4 r1 = cls4[tid + 1024];
    float4 r2 = cls4[tid + 2048];
    float4 r3 = has3 ? cls4[tid + 3072] : make_float4(0.f, 0.f, 0.f, 0.f);

    atomicAdd(&s_hist[skey(r0.x) >> 20], 1);
    atomicAdd(&s_hist[skey(r0.y) >> 20], 1);
    atomicAdd(&s_hist[skey(r0.z) >> 20], 1);
    atomicAdd(&s_hist[skey(r0.w) >> 20], 1);
    atomicAdd(&s_hist[skey(r1.x) >> 20], 1);
    atomicAdd(&s_hist[skey(r1.y) >> 20], 1);
    atomicAdd(&s_hist[skey(r1.z) >> 20], 1);
    atomicAdd(&s_hist[skey(r1.w) >> 20], 1);
    atomicAdd(&s_hist[skey(r2.x) >> 20], 1);
    atomicAdd(&s_hist[skey(r2.y) >> 20], 1);
    atomicAdd(&s_hist[skey(r2.z) >> 20], 1);
    atomicAdd(&s_hist[skey(r2.w) >> 20], 1);
    if (has3) {
        atomicAdd(&s_hist[skey(r3.x) >> 20], 1);
        atomicAdd(&s_hist[skey(r3.y) >> 20], 1);
        atomicAdd(&s_hist[skey(r3.z) >> 20], 1);
        atomicAdd(&s_hist[skey(r3.w) >> 20], 1);
    }
    __syncthreads();

    // ---- Find pivot bin bt: smallest bin with count(bin >= bt) >= NSEL (waves 0-3)
    if (tid < 256) {
        int part = 0;
        #pragma unroll
        for (int i = 0; i < 16; ++i) part += s_hist[tid * 16 + i];
        const int lane = tid & 63, wv = tid >> 6;
        int x = part;
        #pragma unroll
        for (int d2 = 1; d2 < 64; d2 <<= 1) {
            int y = __shfl_up(x, d2, 64);
            if (lane >= d2) x += y;
        }
        if (lane == 63) s_wsum[wv] = x;
        s_S[tid] = part;                       // stash segment count
        s_bufv[tid] = __int_as_float(x);       // stash inclusive wave-scan
    }
    __syncthreads();
    if (tid < 256) {
        const int wv = tid >> 6;
        const int part = s_S[tid];
        const int x = __float_as_int(s_bufv[tid]);
        int offp = 0, tot = 0;
        #pragma unroll
        for (int wq = 0; wq < 4; ++wq) {
            int s = s_wsum[wq];
            tot += s;
            if (wq < wv) offp += s;
        }
        const int Pincl = x + offp;
        const int S = tot - Pincl + part;   // suffix sum over segments >= tid
        s_S[tid] = S;
        if (S >= NSEL) atomicMax(&s_seg, tid);
    }
    __syncthreads();
    if (tid == 0) {
        const int seg = s_seg;
        int acc = (seg < 255) ? s_S[seg + 1] : 0;
        int bt = seg * 16;
        for (int i = 15; i >= 0; --i) {
            int c = s_hist[seg * 16 + i];
            if (acc + c >= NSEL) { bt = seg * 16 + i; break; }
            acc += c;
        }
        s_bt = bt;
    }
    __syncthreads();
    const unsigned bt = (unsigned)s_bt;

    // ---- Pass 2: collect candidates from registers ----
    {
        const int b0 = 4 * tid, b1 = 4 * (tid + 1024), b2 = 4 * (tid + 2048), b3 = 4 * (tid + 3072);
        #define COLL(v, e) if ((skey(v) >> 20) >= bt) { \
            int pos = atomicAdd(&s_cnt, 1); \
            if (pos < BUFCAP) { s_bufv[pos] = (v); s_bufi[pos] = (e); } }
        COLL(r0.x, b0 + 0) COLL(r0.y, b0 + 1) COLL(r0.z, b0 + 2) COLL(r0.w, b0 + 3)
        COLL(r1.x, b1 + 0) COLL(r1.y, b1 + 1) COLL(r1.z, b1 + 2) COLL(r1.w, b1 + 3)
        COLL(r2.x, b2 + 0) COLL(r2.y, b2 + 1) COLL(r2.z, b2 + 2) COLL(r2.w, b2 + 3)
        if (has3) { COLL(r3.x, b3 + 0) COLL(r3.y, b3 + 1) COLL(r3.z, b3 + 2) COLL(r3.w, b3 + 3) }
        #undef COLL
    }
    __syncthreads();
    int C = s_cnt; if (C > BUFCAP) C = BUFCAP;

    // ---- Exact top-20 by rank counting (desc value, tie: lower index first) ----
    for (int j = tid; j < C; j += BLOCK) {
        const float vj = s_bufv[j];
        const int   ij = s_bufi[j];
        int r = 0;
        for (int k = 0; k < C; ++k) {
            const float vk = s_bufv[k];
            const int   ik = s_bufi[k];
            r += (int)((vk > vj) || (vk == vj && ik < ij));
        }
        if (r < NSEL) { s_topv[r] = vj; s_topi[r] = ij; }
    }
    __syncthreads();

    // ---- Decode boxes for the 20 finalists ----
    if (tid < NSEL) {
        s_m[tid] = 0u;
        const float v = s_topv[tid];
        const int   a = s_topi[tid];
        const float score = 1.0f / (1.0f + expf(-v));
        const int z  = a / (DD * DD);
        const int y  = (a / DD) % DD;
        const int xg = a % DD;
        const size_t base3 = (size_t)b * 3 * AA;
        const float o0 = off[base3 + 0 * AA + a];
        const float o1 = off[base3 + 1 * AA + a];
        const float o2 = off[base3 + 2 * AA + a];
        const float s0 = shp[base3 + 0 * AA + a];
        const float s1 = shp[base3 + 1 * AA + a];
        const float s2 = shp[base3 + 2 * AA + a];
        const float cz = ((float)z  + o0) * 4.0f;
        const float cy = ((float)y  + o1) * 4.0f;
        const float cx = ((float)xg + o2) * 4.0f;
        const float ez = 2.0f * s0, ey = 2.0f * s1, ex = 2.0f * s2;
        // mirror reference fp op order exactly
        s_lo[0][tid] = cz - ez * 0.5f;  s_hi[0][tid] = cz + ez * 0.5f;
        s_lo[1][tid] = cy - ey * 0.5f;  s_hi[1][tid] = cy + ey * 0.5f;
        s_lo[2][tid] = cx - ex * 0.5f;  s_hi[2][tid] = cx + ex * 0.5f;
        s_vol[tid]   = (ez * ey) * ex;
        s_det[tid][0] = 1.0f;  s_det[tid][1] = score;
        s_det[tid][2] = cz;    s_det[tid][3] = cy;   s_det[tid][4] = cx;
        s_det[tid][5] = ez;    s_det[tid][6] = ey;   s_det[tid][7] = ex;
    }
    __syncthreads();

    // ---- Parallel IoU suppression masks (400 pairs) + candidate mask ----
    // All valid (>THRESH) entries rank ahead of all invalid ones in value order,
    // so every valid entry in the top-20 is a cand (rank<20 automatic).
    if (tid == BLOCK - 1) {
        unsigned cm = 0u;
        for (int i = 0; i < NSEL; ++i)
            if (s_det[i][1] > THRESH) cm |= (1u << i);
        s_candmask = cm;
    }
    if (tid < NSEL * NSEL) {
        const int i = tid / NSEL, j = tid - i * NSEL;
        if (i != j) {
            const float tz = fmaxf(fminf(s_hi[0][i], s_hi[0][j]) - fmaxf(s_lo[0][i], s_lo[0][j]), 0.0f);
            const float ty = fmaxf(fminf(s_hi[1][i], s_hi[1][j]) - fmaxf(s_lo[1][i], s_lo[1][j]), 0.0f);
            const float tx = fmaxf(fminf(s_hi[2][i], s_hi[2][j]) - fmaxf(s_lo[2][i], s_lo[2][j]), 0.0f);
            const float inter = (tz * ty) * tx;
            const float uni = (s_vol[i] + s_vol[j]) - inter;
            const float iou = inter / fmaxf(uni, 1e-8f);
            if (iou > NMS_THR) atomicOr(&s_m[i], 1u << j);
        }
    }
    __syncthreads();

    // ---- Serial greedy NMS (pure bit ops, thread 0) ----
    if (tid == 0) {
        unsigned supp = 0u, kept = 0u;
        const unsigned cm = s_candmask;
        for (int i = 0; i < NSEL; ++i) {
            const unsigned bit = 1u << i;
            if ((cm & bit) && !(supp & bit)) {
                kept |= bit;
                supp |= s_m[i];
            }
        }
        s_keptmask = kept;
    }
    __syncthreads();

    // ---- Output ----
    const unsigned kept = s_keptmask;
    const int K = __popc(kept);
    float* ob = out + (size_t)b * (TOPK * 8);
    if (tid < NSEL && ((kept >> tid) & 1u)) {
        const int r = __popc(kept & ((1u << tid) - 1u));
        float* row = ob + r * 8;
        #pragma unroll
        for (int q = 0; q < 8; ++q) row[q] = s_det[tid][q];
    }
    const int fill = (TOPK - K) * 8;
    for (int idx = tid; idx < fill; idx += BLOCK) ob[K * 8 + idx] = -1.0f;
}

extern "C" void kernel_launch(void* const* d_in, const int* in_sizes, int n_in,
                              void* d_out, int out_size, void* d_ws, size_t ws_size,
                              hipStream_t stream) {
    (void)n_in; (void)out_size; (void)d_ws; (void)ws_size;
    const float* cls = (const float*)d_in[0];
    const float* shp = (const float*)d_in[1];
    const float* off = (const float*)d_in[2];
    float* out = (float*)d_out;
    const int B = in_sizes[0] / AA;   // 256
    detpost<<<B, BLOCK, 0, stream>>>(cls, shp, off, out);
}